// Round 1
// baseline (127.912 us; speedup 1.0000x reference)
//
#include <hip/hip_runtime.h>
#include <math.h>

#define VFS_EPS 1e-7f

constexpr int V_ = 8, F_ = 64, H_ = 256, W_ = 256, G_ = 128, S_ = 512;
constexpr int HW_ = H_ * W_;

// -------- K0: transpose [V][F][HW] -> [V][HW][F] (channel-last) --------
__global__ __launch_bounds__(256) void vfs_transpose(const float* __restrict__ src,
                                                     float* __restrict__ dst) {
    __shared__ float tile[64][65];
    const int v = blockIdx.y;
    const int p0 = blockIdx.x * 64;
    const int t = threadIdx.x;
    const float* s = src + (size_t)v * F_ * HW_;
    const int pl = t & 63, f0 = t >> 6;
#pragma unroll
    for (int i = 0; i < 16; ++i) {
        const int f = f0 + i * 4;
        tile[f][pl] = s[(size_t)f * HW_ + p0 + pl];
    }
    __syncthreads();
    float* d = dst + (size_t)v * HW_ * F_;
    const int fl = t & 63, q0 = t >> 6;
#pragma unroll
    for (int i = 0; i < 16; ++i) {
        const int p = q0 + i * 4;
        d[(size_t)(p0 + p) * F_ + fl] = tile[fl][p];
    }
}

// -------- K1: project + weight + bilinear sample + weighted mean/var --------
// feat layout: addr = v*HW*F + pix*ps + f*cs   (transposed: ps=F,cs=1; raw: ps=1,cs=HW)
__global__ __launch_bounds__(256) void vfs_sampler(
    const float* __restrict__ feat, const int ps, const int cs,
    const float* __restrict__ Km, const float* __restrict__ Em,
    const float* __restrict__ dst, const float* __restrict__ grids,
    const float* __restrict__ vis, const float* __restrict__ normals,
    const float* __restrict__ cc, float* __restrict__ out) {
    __shared__ float4 wp[64][8];   // {x0 bits, y0 bits, wx, wy} per (s_local, view)
    __shared__ float wv[64][8];    // normalized view weight
    __shared__ float stg[2][64][65]; // [mean|var][s_local][f], padded

    const int g = blockIdx.x >> 3;
    const int sb = (blockIdx.x & 7) * 64;
    const int t = threadIdx.x;
    const int wave = t >> 6;
    const int lane = t & 63;
    const int vL = lane & 7;   // view
    const int pL = lane >> 3;  // point-in-group

    const float nx = normals[g * 3 + 0];
    const float ny = normals[g * 3 + 1];
    const float nz = normals[g * 3 + 2];

    // ---- Phase A: per (point, view) sampling params + normalized weights ----
    for (int grp = 0; grp < 2; ++grp) {
        const int sl = wave * 16 + grp * 8 + pL;
        const int s = sb + sl;
        const float px = grids[(g * 3 + 0) * S_ + s];
        const float py = grids[(g * 3 + 1) * S_ + s];
        const float pz = grids[(g * 3 + 2) * S_ + s];
        const float* Ev = Em + vL * 12;
        const float pi0 = Ev[0] * px + Ev[1] * py + Ev[2] * pz + Ev[3];
        const float pi1 = Ev[4] * px + Ev[5] * py + Ev[6] * pz + Ev[7];
        float z = Ev[8] * px + Ev[9] * py + Ev[10] * pz + Ev[11];
        if (fabsf(z) < VFS_EPS) z = 1.0f;
        const float xn = pi0 / z;
        const float yn = pi1 / z;
        const float r2 = xn * xn + yn * yn;
        const float fd = 1.0f + dst[vL * 2 + 0] * r2 + dst[vL * 2 + 1] * r2 * r2;
        const float xd = xn * fd, yd = yn * fd;
        const float* Kv = Km + vL * 9;
        const float pk0 = Kv[0] * xd + Kv[1] * yd + Kv[2];
        const float pk1 = Kv[3] * xd + Kv[4] * yd + Kv[5];
        const float u = 2.0f * pk0 / (W_ - 1.0f) - 1.0f;
        const float vq = 2.0f * pk1 / (H_ - 1.0f) - 1.0f;
        const bool inside = (u >= -1.0f) && (u <= 1.0f) && (vq >= -1.0f) && (vq <= 1.0f);
        const float x = (u + 1.0f) * (W_ * 0.5f) - 0.5f;
        const float y = (vq + 1.0f) * (H_ * 0.5f) - 0.5f;
        const float x0f = floorf(x), y0f = floorf(y);
        const float wx = x - x0f, wy = y - y0f;
        const int x0 = (int)x0f, y0 = (int)y0f;
        // view-direction / normal incidence
        const float dx = px - cc[vL * 3 + 0];
        const float dy = py - cc[vL * 3 + 1];
        const float dz = pz - cc[vL * 3 + 2];
        float nrm = sqrtf(dx * dx + dy * dy + dz * dz);
        nrm = fmaxf(nrm, 1e-12f);
        float cosv = (dx * nx + dy * ny + dz * nz) / nrm;
        cosv = fminf(cosv, 0.0f);
        const float wraw = vis[vL * G_ + g] * (-cosv) * (inside ? 1.0f : 0.0f);
        const float bx = 50.0f * wraw;
        float w = (bx > 5.0f) ? wraw : (log1pf(expf(bx)) * (1.0f / 50.0f));
        // normalize over the 8 views (lanes sharing pL)
        float wsum = w;
        wsum += __shfl_xor(wsum, 1);
        wsum += __shfl_xor(wsum, 2);
        wsum += __shfl_xor(wsum, 4);
        w = w / wsum;
        wp[sl][vL] = make_float4(__int_as_float(x0), __int_as_float(y0), wx, wy);
        wv[sl][vL] = w;
    }
    __syncthreads();

    // ---- Phase B: lane = channel; gather + weighted accumulate ----
    for (int j = 0; j < 16; ++j) {
        const int sl = wave * 16 + j;
        float mean = 0.0f, m2 = 0.0f;
        for (int v = 0; v < 8; ++v) {
            const float4 q = wp[sl][v];       // broadcast (uniform across wave)
            const float w = wv[sl][v];
            const int x0 = __float_as_int(q.x);
            const int y0 = __float_as_int(q.y);
            const float wx = q.z, wy = q.w;
            const bool vx0 = (x0 >= 0) && (x0 < W_);
            const bool vx1 = (x0 >= -1) && (x0 < W_ - 1);
            const bool vy0 = (y0 >= 0) && (y0 < H_);
            const bool vy1 = (y0 >= -1) && (y0 < H_ - 1);
            if (!((vx0 || vx1) && (vy0 || vy1))) continue;  // feat == 0, skip loads
            const float* base = feat + (size_t)v * HW_ * F_ + (size_t)lane * cs;
            float g00 = 0.f, g01 = 0.f, g10 = 0.f, g11 = 0.f;
            if (vy0) {
                const int row = y0 * W_;
                if (vx0) g00 = base[(size_t)(row + x0) * ps];
                if (vx1) g01 = base[(size_t)(row + x0 + 1) * ps];
            }
            if (vy1) {
                const int row = (y0 + 1) * W_;
                if (vx0) g10 = base[(size_t)(row + x0) * ps];
                if (vx1) g11 = base[(size_t)(row + x0 + 1) * ps];
            }
            const float f00 = (1.f - wx) * (1.f - wy);
            const float f01 = wx * (1.f - wy);
            const float f10 = (1.f - wx) * wy;
            const float f11 = wx * wy;
            const float fe = g00 * f00 + g01 * f01 + g10 * f10 + g11 * f11;
            mean += w * fe;
            m2 += w * fe * fe;
        }
        stg[0][sl][lane] = mean;
        stg[1][sl][lane] = m2 - mean * mean;
    }
    __syncthreads();

    // ---- coalesced write-out: out[g][f][s] and out[g][F+f][s] ----
#pragma unroll
    for (int i = 0; i < 16; ++i) {
        const int e = t + i * 256;
        const int f = e >> 6;
        const int sl = e & 63;
        out[((size_t)(g * 2 * F_ + f)) * S_ + sb + sl] = stg[0][sl][f];
    }
#pragma unroll
    for (int i = 0; i < 16; ++i) {
        const int e = t + i * 256;
        const int f = e >> 6;
        const int sl = e & 63;
        out[((size_t)(g * 2 * F_ + F_ + f)) * S_ + sb + sl] = stg[1][sl][f];
    }
}

extern "C" void kernel_launch(void* const* d_in, const int* in_sizes, int n_in,
                              void* d_out, int out_size, void* d_ws, size_t ws_size,
                              hipStream_t stream) {
    const float* fm      = (const float*)d_in[0]; // [1][8][64][256][256]
    const float* Km      = (const float*)d_in[1]; // [1][8][3][3]
    const float* Em      = (const float*)d_in[2]; // [1][8][3][4]
    const float* dist    = (const float*)d_in[3]; // [1][8][2]
    const float* grids   = (const float*)d_in[4]; // [1][128][3][8][8][8]
    const float* vis     = (const float*)d_in[5]; // [1][8][128]
    const float* normals = (const float*)d_in[6]; // [1][128][3]
    const float* cc      = (const float*)d_in[7]; // [1][8][3]
    float* out           = (float*)d_out;         // [1][128][128][8][8][8]

    const size_t tsize = (size_t)V_ * F_ * HW_ * sizeof(float); // 128 MB
    const float* featsrc = fm;
    int ps = 1, cs = HW_; // raw layout fallback
    if (ws_size >= tsize) {
        vfs_transpose<<<dim3(HW_ / 64, V_), 256, 0, stream>>>(fm, (float*)d_ws);
        featsrc = (const float*)d_ws;
        ps = F_;
        cs = 1;
    }
    vfs_sampler<<<G_ * 8, 256, 0, stream>>>(featsrc, ps, cs, Km, Em, dist, grids,
                                            vis, normals, cc, out);
}

// Round 2
// 103.728 us; speedup vs baseline: 1.2332x; 1.2332x over previous
//
#include <hip/hip_runtime.h>
#include <math.h>

#define VFS_EPS 1e-7f

constexpr int V_ = 8, F_ = 64, H_ = 256, W_ = 256, G_ = 128, S_ = 512;
constexpr int HW_ = H_ * W_;

// -------- K0: transpose [V][F][HW] -> [V][HW][F], float4 both sides --------
__global__ __launch_bounds__(256) void vfs_transpose(const float* __restrict__ src,
                                                     float* __restrict__ dst) {
    __shared__ float T[64][65];
    const int v = blockIdx.y;
    const int p0 = blockIdx.x * 64;
    const int t = threadIdx.x;
    const float* s = src + (size_t)v * F_ * HW_;
    {
        const int c4 = t & 15;   // pixel quad (16 quads = 64 px)
        const int f0 = t >> 4;   // 16 channel rows per pass
#pragma unroll
        for (int i = 0; i < 4; ++i) {
            const int f = f0 + i * 16;
            const float4 val = *reinterpret_cast<const float4*>(&s[(size_t)f * HW_ + p0 + c4 * 4]);
            T[c4 * 4 + 0][f] = val.x;
            T[c4 * 4 + 1][f] = val.y;
            T[c4 * 4 + 2][f] = val.z;
            T[c4 * 4 + 3][f] = val.w;
        }
    }
    __syncthreads();
    float* d = dst + (size_t)v * HW_ * F_;
    {
        const int f4 = t & 15;   // channel quad (16 quads = 64 ch)
        const int q0 = t >> 4;
#pragma unroll
        for (int i = 0; i < 4; ++i) {
            const int p = q0 + i * 16;
            float4 val;
            val.x = T[p][f4 * 4 + 0];
            val.y = T[p][f4 * 4 + 1];
            val.z = T[p][f4 * 4 + 2];
            val.w = T[p][f4 * 4 + 3];
            *reinterpret_cast<float4*>(&d[(size_t)(p0 + p) * F_ + f4 * 4]) = val;
        }
    }
}

// -------- K1: project + weight + bilinear sample + weighted mean/var --------
// PS = pixel stride (elements), CS = channel stride. Transposed: PS=F, CS=1.
template <int PS, int CS>
__global__ __launch_bounds__(256) void vfs_sampler(
    const float* __restrict__ feat,
    const float* __restrict__ Km, const float* __restrict__ Em,
    const float* __restrict__ dst, const float* __restrict__ grids,
    const float* __restrict__ vis, const float* __restrict__ normals,
    const float* __restrict__ cc, float* __restrict__ out) {
    __shared__ float4 wp[64][8];   // {x0 bits, y0 bits, wx, wy} per (s_local, view)
    __shared__ float wv[64][8];    // normalized view weight
    __shared__ float stg[64][65];  // staging for coalesced writeout

    const int g = blockIdx.x >> 3;
    const int sb = (blockIdx.x & 7) * 64;
    const int t = threadIdx.x;
    const int wave = t >> 6;
    const int lane = t & 63;
    const int vL = lane & 7;   // view
    const int pL = lane >> 3;  // point-in-group

    const float nx = normals[g * 3 + 0];
    const float ny = normals[g * 3 + 1];
    const float nz = normals[g * 3 + 2];

    // ---- Phase A: per (point, view) sampling params + normalized weights ----
#pragma unroll
    for (int grp = 0; grp < 2; ++grp) {
        const int sl = wave * 16 + grp * 8 + pL;
        const int s = sb + sl;
        const float px = grids[(g * 3 + 0) * S_ + s];
        const float py = grids[(g * 3 + 1) * S_ + s];
        const float pz = grids[(g * 3 + 2) * S_ + s];
        const float* Ev = Em + vL * 12;
        const float pi0 = Ev[0] * px + Ev[1] * py + Ev[2] * pz + Ev[3];
        const float pi1 = Ev[4] * px + Ev[5] * py + Ev[6] * pz + Ev[7];
        float z = Ev[8] * px + Ev[9] * py + Ev[10] * pz + Ev[11];
        if (fabsf(z) < VFS_EPS) z = 1.0f;
        const float xn = pi0 / z;
        const float yn = pi1 / z;
        const float r2 = xn * xn + yn * yn;
        const float fd = 1.0f + dst[vL * 2 + 0] * r2 + dst[vL * 2 + 1] * r2 * r2;
        const float xd = xn * fd, yd = yn * fd;
        const float* Kv = Km + vL * 9;
        const float pk0 = Kv[0] * xd + Kv[1] * yd + Kv[2];
        const float pk1 = Kv[3] * xd + Kv[4] * yd + Kv[5];
        const float u = 2.0f * pk0 / (W_ - 1.0f) - 1.0f;
        const float vq = 2.0f * pk1 / (H_ - 1.0f) - 1.0f;
        const bool inside = (u >= -1.0f) && (u <= 1.0f) && (vq >= -1.0f) && (vq <= 1.0f);
        const float x = (u + 1.0f) * (W_ * 0.5f) - 0.5f;
        const float y = (vq + 1.0f) * (H_ * 0.5f) - 0.5f;
        const float x0f = floorf(x), y0f = floorf(y);
        const float wx = x - x0f, wy = y - y0f;
        const int x0 = (int)x0f, y0 = (int)y0f;
        // view-direction / normal incidence
        const float dx = px - cc[vL * 3 + 0];
        const float dy = py - cc[vL * 3 + 1];
        const float dz = pz - cc[vL * 3 + 2];
        float nrm = sqrtf(dx * dx + dy * dy + dz * dz);
        nrm = fmaxf(nrm, 1e-12f);
        float cosv = (dx * nx + dy * ny + dz * nz) / nrm;
        cosv = fminf(cosv, 0.0f);
        const float wraw = vis[vL * G_ + g] * (-cosv) * (inside ? 1.0f : 0.0f);
        const float bx = 50.0f * wraw;
        float w = (bx > 5.0f) ? wraw : (log1pf(expf(bx)) * (1.0f / 50.0f));
        // normalize over the 8 views (lanes sharing pL)
        float wsum = w;
        wsum += __shfl_xor(wsum, 1);
        wsum += __shfl_xor(wsum, 2);
        wsum += __shfl_xor(wsum, 4);
        w = w / wsum;
        wp[sl][vL] = make_float4(__int_as_float(x0), __int_as_float(y0), wx, wy);
        wv[sl][vL] = w;
    }
    __syncthreads();

    // ---- Phase B: lane = channel; branchless clamped gather + accumulate ----
    float mean[16], var[16];
#pragma unroll 2
    for (int j = 0; j < 16; ++j) {
        const int sl = wave * 16 + j;
        float m = 0.0f, m2 = 0.0f;
#pragma unroll
        for (int v = 0; v < 8; ++v) {
            const float4 q = wp[sl][v];       // broadcast (uniform across wave)
            const float w = wv[sl][v];
            const int x0 = __float_as_int(q.x);
            const int y0 = __float_as_int(q.y);
            const float wx = q.z, wy = q.w;
            const bool vx0 = (x0 >= 0) & (x0 < W_);
            const bool vx1 = (x0 >= -1) & (x0 < W_ - 1);
            const bool vy0 = (y0 >= 0) & (y0 < H_);
            const bool vy1 = (y0 >= -1) & (y0 < H_ - 1);
            const int xc0 = min(max(x0, 0), W_ - 1);
            const int xc1 = min(max(x0 + 1, 0), W_ - 1);
            const int yc0 = min(max(y0, 0), H_ - 1);
            const int yc1 = min(max(y0 + 1, 0), H_ - 1);
            const float* base = feat + (size_t)v * ((size_t)HW_ * F_) + (size_t)lane * CS;
            const float g00 = base[(size_t)(yc0 * W_ + xc0) * PS];
            const float g01 = base[(size_t)(yc0 * W_ + xc1) * PS];
            const float g10 = base[(size_t)(yc1 * W_ + xc0) * PS];
            const float g11 = base[(size_t)(yc1 * W_ + xc1) * PS];
            const float f00 = (vx0 & vy0) ? (1.f - wx) * (1.f - wy) : 0.f;
            const float f01 = (vx1 & vy0) ? wx * (1.f - wy) : 0.f;
            const float f10 = (vx0 & vy1) ? (1.f - wx) * wy : 0.f;
            const float f11 = (vx1 & vy1) ? wx * wy : 0.f;
            const float fe = g00 * f00 + g01 * f01 + g10 * f10 + g11 * f11;
            m += w * fe;
            m2 += w * fe * fe;
        }
        mean[j] = m;
        var[j] = m2 - m * m;
    }

    // ---- coalesced write-out via single staging buffer, two passes ----
#pragma unroll
    for (int j = 0; j < 16; ++j) stg[wave * 16 + j][lane] = mean[j];
    __syncthreads();
#pragma unroll
    for (int i = 0; i < 16; ++i) {
        const int e = t + i * 256;
        const int f = e >> 6;
        const int sl = e & 63;
        out[((size_t)(g * 2 * F_ + f)) * S_ + sb + sl] = stg[sl][f];
    }
    __syncthreads();
#pragma unroll
    for (int j = 0; j < 16; ++j) stg[wave * 16 + j][lane] = var[j];
    __syncthreads();
#pragma unroll
    for (int i = 0; i < 16; ++i) {
        const int e = t + i * 256;
        const int f = e >> 6;
        const int sl = e & 63;
        out[((size_t)(g * 2 * F_ + F_ + f)) * S_ + sb + sl] = stg[sl][f];
    }
}

extern "C" void kernel_launch(void* const* d_in, const int* in_sizes, int n_in,
                              void* d_out, int out_size, void* d_ws, size_t ws_size,
                              hipStream_t stream) {
    const float* fm      = (const float*)d_in[0]; // [1][8][64][256][256]
    const float* Km      = (const float*)d_in[1]; // [1][8][3][3]
    const float* Em      = (const float*)d_in[2]; // [1][8][3][4]
    const float* dist    = (const float*)d_in[3]; // [1][8][2]
    const float* grids   = (const float*)d_in[4]; // [1][128][3][8][8][8]
    const float* vis     = (const float*)d_in[5]; // [1][8][128]
    const float* normals = (const float*)d_in[6]; // [1][128][3]
    const float* cc      = (const float*)d_in[7]; // [1][8][3]
    float* out           = (float*)d_out;         // [1][128][128][8][8][8]

    const size_t tsize = (size_t)V_ * F_ * HW_ * sizeof(float); // 128 MB
    if (ws_size >= tsize) {
        vfs_transpose<<<dim3(HW_ / 64, V_), 256, 0, stream>>>(fm, (float*)d_ws);
        vfs_sampler<F_, 1><<<G_ * 8, 256, 0, stream>>>((const float*)d_ws, Km, Em, dist,
                                                       grids, vis, normals, cc, out);
    } else {
        vfs_sampler<1, HW_><<<G_ * 8, 256, 0, stream>>>(fm, Km, Em, dist,
                                                        grids, vis, normals, cc, out);
    }
}